// Round 2
// baseline (1267.355 us; speedup 1.0000x reference)
//
#include <hip/hip_runtime.h>
#include <hip/hip_bf16.h>

// N=50000 nodes, E=800000 edges, D_IN=500, D_POS=2, LATENT=128, C=10
#define NEG_SLOPE 0.2f

// ---------------------------------------------------------------------------
// GEMM: C[nrows,M] = act(A[nrows,K] @ B[K,M] + bias)
// BM=BN=128, BK=16, 256 threads, 8x8 micro-tile per thread (f32 vector ALU).
// CONCAT=1: A is concat(x[N,500], pos[N,2], zero-pad to 512); B rows >= klimit -> 0.
// ---------------------------------------------------------------------------
template<int CONCAT>
__global__ __launch_bounds__(256)
void gemm_kernel(const float* __restrict__ A, const float* __restrict__ pos,
                 const float* __restrict__ B, const float* __restrict__ bias,
                 float* __restrict__ C, int nrows, int K, int M, int klimit, int do_relu)
{
    __shared__ float As[16][128];   // transposed tile: As[k][m]
    __shared__ float Bs[16][128];   // Bs[k][n]
    const int t    = threadIdx.x;
    const int row0 = blockIdx.x * 128;
    const int col0 = blockIdx.y * 128;
    const int tx   = t & 15;        // 16 col groups of 8
    const int ty   = t >> 4;        // 16 row groups of 8

    float acc[8][8];
    #pragma unroll
    for (int i = 0; i < 8; ++i)
        #pragma unroll
        for (int j = 0; j < 8; ++j) acc[i][j] = 0.f;

    for (int k0 = 0; k0 < K; k0 += 16) {
        // ---- stage A tile (128 rows x 16 k), transposed into As[k][m]
        #pragma unroll
        for (int i = 0; i < 2; ++i) {
            int slot = t + i * 256;
            int m  = slot >> 2;
            int k4 = (slot & 3) * 4;
            int grow = row0 + m;
            if (CONCAT) {
                #pragma unroll
                for (int j = 0; j < 4; ++j) {
                    int k = k0 + k4 + j;
                    float v = 0.f;
                    if (grow < nrows) {
                        if (k < 500)      v = A[(size_t)grow * 500 + k];
                        else if (k < 502) v = pos[(size_t)grow * 2 + (k - 500)];
                    }
                    As[k4 + j][m] = v;
                }
            } else {
                float4 v = make_float4(0.f, 0.f, 0.f, 0.f);
                if (grow < nrows)
                    v = *(const float4*)(A + (size_t)grow * K + k0 + k4);
                As[k4 + 0][m] = v.x; As[k4 + 1][m] = v.y;
                As[k4 + 2][m] = v.z; As[k4 + 3][m] = v.w;
            }
        }
        // ---- stage B tile (16 k x 128 n)
        #pragma unroll
        for (int i = 0; i < 2; ++i) {
            int slot = t + i * 256;
            int k  = slot >> 5;
            int n4 = (slot & 31) * 4;
            float4 v = make_float4(0.f, 0.f, 0.f, 0.f);
            int gk = k0 + k;
            if (gk < klimit && (col0 + n4) < M)
                v = *(const float4*)(B + (size_t)gk * M + col0 + n4);
            *(float4*)&Bs[k][n4] = v;
        }
        __syncthreads();

        // ---- 8x8 micro-tile FMA
        #pragma unroll
        for (int k = 0; k < 16; ++k) {
            float4 a0 = *(const float4*)&As[k][ty * 8];
            float4 a1 = *(const float4*)&As[k][ty * 8 + 4];
            float4 b0 = *(const float4*)&Bs[k][tx * 8];
            float4 b1 = *(const float4*)&Bs[k][tx * 8 + 4];
            float av[8] = {a0.x, a0.y, a0.z, a0.w, a1.x, a1.y, a1.z, a1.w};
            float bv[8] = {b0.x, b0.y, b0.z, b0.w, b1.x, b1.y, b1.z, b1.w};
            #pragma unroll
            for (int i = 0; i < 8; ++i)
                #pragma unroll
                for (int j = 0; j < 8; ++j)
                    acc[i][j] += av[i] * bv[j];
        }
        __syncthreads();
    }

    // ---- epilogue: bias + optional relu
    #pragma unroll
    for (int i = 0; i < 8; ++i) {
        int grow = row0 + ty * 8 + i;
        if (grow >= nrows) continue;
        #pragma unroll
        for (int j = 0; j < 8; ++j) {
            int gcol = col0 + tx * 8 + j;
            if (gcol >= M) continue;
            float v = acc[i][j] + bias[gcol];
            if (do_relu) v = fmaxf(v, 0.f);
            C[(size_t)grow * M + gcol] = v;
        }
    }
}

// ---------------------------------------------------------------------------
// CSR build
// ---------------------------------------------------------------------------
__global__ void init_cnt_kernel(int* cnt, int n)
{
    for (int i = blockIdx.x * blockDim.x + threadIdx.x; i < n;
         i += gridDim.x * blockDim.x)
        cnt[i] = 0;
}

__global__ void count_edges_kernel(const int* __restrict__ dst, int* cnt, int E)
{
    int e = blockIdx.x * blockDim.x + threadIdx.x;
    if (e < E) atomicAdd(&cnt[dst[e]], 1);
}

// single-block exclusive scan over n counts -> row_start[0..n], cursor[i]=row_start[i]
__global__ __launch_bounds__(1024)
void scan_kernel(const int* __restrict__ cnt, int* row_start, int* cursor, int n)
{
    __shared__ int sh[1024];
    __shared__ int carry_sh;
    const int t = threadIdx.x;
    if (t == 0) carry_sh = 0;
    __syncthreads();
    for (int base = 0; base < n; base += 1024) {
        int i = base + t;
        int v = (i < n) ? cnt[i] : 0;
        sh[t] = v;
        __syncthreads();
        #pragma unroll
        for (int off = 1; off < 1024; off <<= 1) {
            int x = (t >= off) ? sh[t - off] : 0;
            __syncthreads();
            sh[t] += x;
            __syncthreads();
        }
        int inc   = sh[t];          // inclusive scan of this chunk
        int carry = carry_sh;
        if (i < n) {
            int ex = carry + inc - v;
            row_start[i] = ex;
            cursor[i]    = ex;
        }
        __syncthreads();
        if (t == 1023) carry_sh = carry + sh[1023];
        __syncthreads();
    }
    if (t == 0) row_start[n] = carry_sh;
}

__global__ void scatter_edges_kernel(const int* __restrict__ dst, int* cursor,
                                     int* eid, int E)
{
    int e = blockIdx.x * blockDim.x + threadIdx.x;
    if (e < E) {
        int p = atomicAdd(&cursor[dst[e]], 1);
        eid[p] = e;
    }
}

// ---------------------------------------------------------------------------
// Fused GATv2 aggregation: one wave per dst node, online softmax over its
// incoming edges; z = relu(agg + bg). Lane l owns dims {2l, 2l+1}.
// ---------------------------------------------------------------------------
__global__ __launch_bounds__(256)
void gat_aggregate_kernel(const float* __restrict__ xl, const float* __restrict__ xr,
                          const int* __restrict__ srcArr, const float* __restrict__ eattr,
                          const float* __restrict__ We, const float* __restrict__ att,
                          const float* __restrict__ bg, const int* __restrict__ row_start,
                          const int* __restrict__ eid, float* __restrict__ z, int n)
{
    const int wave = threadIdx.x >> 6;
    const int lane = threadIdx.x & 63;
    const int node = blockIdx.x * 4 + wave;
    if (node >= n) return;

    const float2 att2 = *(const float2*)(att + lane * 2);
    const float2 we2  = *(const float2*)(We + lane * 2);
    const float2 xr2  = *(const float2*)(xr + (size_t)node * 128 + lane * 2);
    const float2 bg2  = *(const float2*)(bg + lane * 2);

    const int beg = row_start[node];
    const int end = row_start[node + 1];

    float m_run = -INFINITY;
    float l_run = 0.f;
    float accx = 0.f, accy = 0.f;

    for (int idx = beg; idx < end; ++idx) {
        int e = eid[idx];
        int s = srcArr[e];
        float ea = eattr[e];
        float2 xl2 = *(const float2*)(xl + (size_t)s * 128 + lane * 2);
        float mx = xl2.x + xr2.x + ea * we2.x;
        float my = xl2.y + xr2.y + ea * we2.y;
        mx = (mx > 0.f) ? mx : NEG_SLOPE * mx;
        my = (my > 0.f) ? my : NEG_SLOPE * my;
        float part = mx * att2.x + my * att2.y;
        #pragma unroll
        for (int off = 1; off < 64; off <<= 1)
            part += __shfl_xor(part, off);
        // online softmax update
        float mn = fmaxf(m_run, part);
        float sc = expf(m_run - mn);   // 0 on first iter (m_run=-inf)
        float p  = expf(part - mn);
        l_run = l_run * sc + p;
        accx  = accx * sc + p * xl2.x;
        accy  = accy * sc + p * xl2.y;
        m_run = mn;
    }

    float inv = (l_run > 0.f) ? 1.f / l_run : 0.f;
    float zx = accx * inv + bg2.x;
    float zy = accy * inv + bg2.y;
    zx = fmaxf(zx, 0.f);
    zy = fmaxf(zy, 0.f);
    *(float2*)(z + (size_t)node * 128 + lane * 2) = make_float2(zx, zy);
}

// ---------------------------------------------------------------------------
// Decoder layer 2 + softmax, f32 output. One thread per node.
// ---------------------------------------------------------------------------
__global__ __launch_bounds__(256)
void dec2_softmax_kernel(const float* __restrict__ d, const float* __restrict__ Wd2,
                         const float* __restrict__ bd2, float* __restrict__ out,
                         int n)
{
    __shared__ float w[64 * 10];
    __shared__ float b[10];
    const int t = threadIdx.x;
    for (int i = t; i < 640; i += 256) w[i] = Wd2[i];
    if (t < 10) b[t] = bd2[t];
    __syncthreads();

    int node = blockIdx.x * 256 + t;
    if (node >= n) return;

    const float* dr = d + (size_t)node * 64;
    float logits[10];
    #pragma unroll
    for (int c = 0; c < 10; ++c) logits[c] = b[c];
    for (int k = 0; k < 64; k += 4) {
        float4 dv = *(const float4*)(dr + k);
        #pragma unroll
        for (int c = 0; c < 10; ++c) {
            logits[c] += dv.x * w[(k + 0) * 10 + c];
            logits[c] += dv.y * w[(k + 1) * 10 + c];
            logits[c] += dv.z * w[(k + 2) * 10 + c];
            logits[c] += dv.w * w[(k + 3) * 10 + c];
        }
    }
    float mx = logits[0];
    #pragma unroll
    for (int c = 1; c < 10; ++c) mx = fmaxf(mx, logits[c]);
    float ssum = 0.f;
    #pragma unroll
    for (int c = 0; c < 10; ++c) { logits[c] = expf(logits[c] - mx); ssum += logits[c]; }
    float inv = 1.f / ssum;
    #pragma unroll
    for (int c = 0; c < 10; ++c)
        out[(size_t)node * 10 + c] = logits[c] * inv;
}

// ---------------------------------------------------------------------------
// Launch
// ---------------------------------------------------------------------------
extern "C" void kernel_launch(void* const* d_in, const int* in_sizes, int n_in,
                              void* d_out, int out_size, void* d_ws, size_t ws_size,
                              hipStream_t stream)
{
    const float* x    = (const float*)d_in[0];
    const float* pos  = (const float*)d_in[1];
    const int*   ei   = (const int*)d_in[2];
    const float* ea   = (const float*)d_in[3];
    const float* W1   = (const float*)d_in[4];
    const float* b1   = (const float*)d_in[5];
    const float* W2   = (const float*)d_in[6];
    const float* b2   = (const float*)d_in[7];
    const float* W3   = (const float*)d_in[8];
    const float* b3   = (const float*)d_in[9];
    const float* Wl   = (const float*)d_in[10];
    const float* bl   = (const float*)d_in[11];
    const float* Wr   = (const float*)d_in[12];
    const float* br   = (const float*)d_in[13];
    const float* We   = (const float*)d_in[14];
    const float* att  = (const float*)d_in[15];
    const float* bg   = (const float*)d_in[16];
    const float* Wd1  = (const float*)d_in[17];
    const float* bd1  = (const float*)d_in[18];
    const float* Wd2  = (const float*)d_in[19];
    const float* bd2  = (const float*)d_in[20];
    float* out = (float*)d_out;   // reference returns f32 softmax

    const int N = in_sizes[0] / 500;   // 50000
    const int E = in_sizes[2] / 2;     // 800000

    // workspace layout (floats); peak = N*768 floats = 153.6 MB
    float* W = (float*)d_ws;
    float* h1 = W;                         // [0, N*512)
    float* h2 = W + (size_t)N * 512;       // [N*512, N*768)
    // h1 dead after h2 computed; recycle its region:
    float* h  = W;                         // [0, N*128)
    float* xl = W + (size_t)N * 128;       // [N*128, N*256)
    float* xr = W + (size_t)N * 256;       // [N*256, N*384)
    int*   cnt       = (int*)(W + (size_t)N * 384);   // N ints (also cursor)
    int*   row_start = cnt + N;                       // N+1 ints
    int*   eid       = row_start + N + 1;             // E ints
    float* z  = W + (size_t)N * 384 + 1000000;        // N*128
    float* dd = z + (size_t)N * 128;                  // N*64

    const int* srcArr = ei;
    const int* dstArr = ei + E;

    const int gx = (N + 127) / 128;

    // encoder
    gemm_kernel<1><<<dim3(gx, 4), 256, 0, stream>>>(x, pos, W1, b1, h1, N, 512, 512, 502, 1);
    gemm_kernel<0><<<dim3(gx, 2), 256, 0, stream>>>(h1, nullptr, W2, b2, h2, N, 512, 256, 512, 1);
    gemm_kernel<0><<<dim3(gx, 1), 256, 0, stream>>>(h2, nullptr, W3, b3, h,  N, 256, 128, 256, 0);
    // GATv2 node transforms
    gemm_kernel<0><<<dim3(gx, 1), 256, 0, stream>>>(h, nullptr, Wl, bl, xl, N, 128, 128, 128, 0);
    gemm_kernel<0><<<dim3(gx, 1), 256, 0, stream>>>(h, nullptr, Wr, br, xr, N, 128, 128, 128, 0);

    // CSR by dst
    init_cnt_kernel<<<256, 256, 0, stream>>>(cnt, N);
    count_edges_kernel<<<(E + 255) / 256, 256, 0, stream>>>(dstArr, cnt, E);
    scan_kernel<<<1, 1024, 0, stream>>>(cnt, row_start, cnt, N);
    scatter_edges_kernel<<<(E + 255) / 256, 256, 0, stream>>>(dstArr, cnt, eid, E);

    // fused GATv2 edge-softmax + aggregation + bias + relu
    gat_aggregate_kernel<<<(N + 3) / 4, 256, 0, stream>>>(xl, xr, srcArr, ea, We, att, bg,
                                                          row_start, eid, z, N);

    // decoder
    gemm_kernel<0><<<dim3(gx, 1), 256, 0, stream>>>(z, nullptr, Wd1, bd1, dd, N, 128, 64, 128, 1);
    dec2_softmax_kernel<<<(N + 255) / 256, 256, 0, stream>>>(dd, Wd2, bd2, out, N);
}

// Round 3
// 571.853 us; speedup vs baseline: 2.2162x; 2.2162x over previous
//
#include <hip/hip_runtime.h>
#include <hip/hip_bf16.h>

// N=50000 nodes, E=800000 edges, D_IN=500, D_POS=2, LATENT=128, C=10
#define NEG_SLOPE 0.2f

typedef _Float16 half8  __attribute__((ext_vector_type(8)));
typedef _Float16 half2v __attribute__((ext_vector_type(2)));
typedef float   float4v __attribute__((ext_vector_type(4)));

// ---------------------------------------------------------------------------
// concat(x,pos) -> f16 [N x 512], cols 502..511 zero
// ---------------------------------------------------------------------------
__global__ __launch_bounds__(256)
void concat_f16_kernel(const float* __restrict__ x, const float* __restrict__ pos,
                       _Float16* __restrict__ A0, int N)
{
    const int total = N * 256;            // each thread: 2 consecutive cols
    for (int i = blockIdx.x * 256 + threadIdx.x; i < total; i += gridDim.x * 256) {
        int node = i >> 8;
        int c2   = (i & 255) * 2;
        float2 v = make_float2(0.f, 0.f);
        if (c2 < 500)       v = *(const float2*)(x + (size_t)node * 500 + c2);
        else if (c2 == 500) v = *(const float2*)(pos + (size_t)node * 2);
        half2v h; h.x = (_Float16)v.x; h.y = (_Float16)v.y;
        *(half2v*)(A0 + (size_t)node * 512 + c2) = h;
    }
}

// ---------------------------------------------------------------------------
// weight convert + transpose: W f32 [K x Nout] -> Wt f16 [Nout x Kpad], pad k>=K with 0
// ---------------------------------------------------------------------------
__global__ void wconv_kernel(const float* __restrict__ W, _Float16* __restrict__ Wt,
                             int K, int Nout, int Kpad)
{
    int total = Nout * Kpad;
    for (int i = blockIdx.x * blockDim.x + threadIdx.x; i < total;
         i += gridDim.x * blockDim.x) {
        int n = i / Kpad, k = i - n * Kpad;
        Wt[i] = (_Float16)((k < K) ? W[(size_t)k * Nout + n] : 0.f);
    }
}

// ---------------------------------------------------------------------------
// f16 MFMA GEMM: C[M,N] = act(A[M,K]f16 @ B[K,N] + bias), B given TRANSPOSED
// as Bt[N,K] f16. 128x128 tile, BK=32, 4 waves (2x2), wave = 64x64 via 4x4
// mfma_f32_16x16x32_f16. LDS row pitch 40 f16 (bank-conflict-free).
// WF32: write f32 C; WF16: write f16 C.
// ---------------------------------------------------------------------------
template<int WF32, int WF16>
__global__ __launch_bounds__(256)
void gemm_f16_kernel(const _Float16* __restrict__ A, const _Float16* __restrict__ Bt,
                     const float* __restrict__ bias, float* __restrict__ Cf,
                     _Float16* __restrict__ Ch, int M, int N, int K, int do_relu)
{
    __shared__ __align__(16) _Float16 As[128 * 40];
    __shared__ __align__(16) _Float16 Bs[128 * 40];

    const int t    = threadIdx.x;
    const int row0 = blockIdx.x * 128;
    const int n0   = blockIdx.y * 128;
    const int K8   = K >> 3;            // uint4 (8 f16) per row
    const int lane = t & 63;
    const int w    = t >> 6;
    const int wrow = (w >> 1) * 64;
    const int wcol = (w & 1) * 64;
    const int lrow = lane & 15;
    const int lk   = lane >> 4;

    const int r0 = t >> 2;              // staging row (0..63), +64 for slot 1
    const int kq = t & 3;               // which 16B chunk of the 64B row

    const uint4* Ag = (const uint4*)A;
    const uint4* Bg = (const uint4*)Bt;

    float4v acc[4][4];
    #pragma unroll
    for (int i = 0; i < 4; ++i)
        #pragma unroll
        for (int j = 0; j < 4; ++j)
            acc[i][j] = (float4v){0.f, 0.f, 0.f, 0.f};

    const int KT = K >> 5;
    uint4 ra[2], rb[2];

    auto load_tile = [&](int kt) {
        int kb = kt * 4;                // k0/8
        #pragma unroll
        for (int i = 0; i < 2; ++i) {
            int row = r0 + i * 64;
            int gr  = row0 + row;
            int gc  = n0 + row;
            uint4 za; za.x = za.y = za.z = za.w = 0u;
            uint4 zb; zb.x = zb.y = zb.z = zb.w = 0u;
            if (gr < M) za = Ag[(size_t)gr * K8 + kb + kq];
            if (gc < N) zb = Bg[(size_t)gc * K8 + kb + kq];
            ra[i] = za; rb[i] = zb;
        }
    };
    auto store_tile = [&]() {
        #pragma unroll
        for (int i = 0; i < 2; ++i) {
            int row = r0 + i * 64;
            *(uint4*)&As[row * 40 + kq * 8] = ra[i];
            *(uint4*)&Bs[row * 40 + kq * 8] = rb[i];
        }
    };

    load_tile(0);
    store_tile();
    __syncthreads();

    for (int kt = 0; kt < KT; ++kt) {
        if (kt + 1 < KT) load_tile(kt + 1);

        half8 af[4], bf[4];
        #pragma unroll
        for (int mi = 0; mi < 4; ++mi)
            af[mi] = *(const half8*)&As[(wrow + mi * 16 + lrow) * 40 + lk * 8];
        #pragma unroll
        for (int ni = 0; ni < 4; ++ni)
            bf[ni] = *(const half8*)&Bs[(wcol + ni * 16 + lrow) * 40 + lk * 8];

        #pragma unroll
        for (int mi = 0; mi < 4; ++mi)
            #pragma unroll
            for (int ni = 0; ni < 4; ++ni)
                acc[mi][ni] = __builtin_amdgcn_mfma_f32_16x16x32_f16(
                    af[mi], bf[ni], acc[mi][ni], 0, 0, 0);

        __syncthreads();
        if (kt + 1 < KT) { store_tile(); __syncthreads(); }
    }

    // epilogue: C[row = (lane>>4)*4 + r, col = lane&15] per 16x16 tile
    #pragma unroll
    for (int mi = 0; mi < 4; ++mi) {
        #pragma unroll
        for (int ni = 0; ni < 4; ++ni) {
            #pragma unroll
            for (int r = 0; r < 4; ++r) {
                int row = row0 + wrow + mi * 16 + lk * 4 + r;
                int col = n0 + wcol + ni * 16 + lrow;
                if (row < M && col < N) {
                    float v = acc[mi][ni][r] + bias[col];
                    if (do_relu) v = fmaxf(v, 0.f);
                    if (WF32) Cf[(size_t)row * N + col] = v;
                    if (WF16) Ch[(size_t)row * N + col] = (_Float16)v;
                }
            }
        }
    }
}

// ---------------------------------------------------------------------------
// CSR build
// ---------------------------------------------------------------------------
__global__ void init_cnt_kernel(int* cnt, int n)
{
    for (int i = blockIdx.x * blockDim.x + threadIdx.x; i < n;
         i += gridDim.x * blockDim.x)
        cnt[i] = 0;
}

__global__ void count_edges_kernel(const int* __restrict__ dst, int* cnt, int E)
{
    int e = blockIdx.x * blockDim.x + threadIdx.x;
    if (e < E) atomicAdd(&cnt[dst[e]], 1);
}

__global__ __launch_bounds__(1024)
void scan_kernel(const int* __restrict__ cnt, int* row_start, int* cursor, int n)
{
    __shared__ int sh[1024];
    __shared__ int carry_sh;
    const int t = threadIdx.x;
    if (t == 0) carry_sh = 0;
    __syncthreads();
    for (int base = 0; base < n; base += 1024) {
        int i = base + t;
        int v = (i < n) ? cnt[i] : 0;
        sh[t] = v;
        __syncthreads();
        #pragma unroll
        for (int off = 1; off < 1024; off <<= 1) {
            int xv = (t >= off) ? sh[t - off] : 0;
            __syncthreads();
            sh[t] += xv;
            __syncthreads();
        }
        int inc   = sh[t];
        int carry = carry_sh;
        if (i < n) {
            int ex = carry + inc - v;
            row_start[i] = ex;
            cursor[i]    = ex;
        }
        __syncthreads();
        if (t == 1023) carry_sh = carry + sh[1023];
        __syncthreads();
    }
    if (t == 0) row_start[n] = carry_sh;
}

__global__ void scatter_edges_kernel(const int* __restrict__ dst, int* cursor,
                                     int* eid, int E)
{
    int e = blockIdx.x * blockDim.x + threadIdx.x;
    if (e < E) {
        int p = atomicAdd(&cursor[dst[e]], 1);
        eid[p] = e;
    }
}

// ---------------------------------------------------------------------------
// Fused GATv2: one wave per dst node, online softmax; z = relu(agg+bg) -> f16
// ---------------------------------------------------------------------------
__global__ __launch_bounds__(256)
void gat_aggregate_kernel(const float* __restrict__ xl, const float* __restrict__ xr,
                          const int* __restrict__ srcArr, const float* __restrict__ eattr,
                          const float* __restrict__ We, const float* __restrict__ att,
                          const float* __restrict__ bg, const int* __restrict__ row_start,
                          const int* __restrict__ eid, _Float16* __restrict__ z, int n)
{
    const int wave = threadIdx.x >> 6;
    const int lane = threadIdx.x & 63;
    const int node = blockIdx.x * 4 + wave;
    if (node >= n) return;

    const float2 att2 = *(const float2*)(att + lane * 2);
    const float2 we2  = *(const float2*)(We + lane * 2);
    const float2 xr2  = *(const float2*)(xr + (size_t)node * 128 + lane * 2);
    const float2 bg2  = *(const float2*)(bg + lane * 2);

    const int beg = row_start[node];
    const int end = row_start[node + 1];

    float m_run = -INFINITY;
    float l_run = 0.f;
    float accx = 0.f, accy = 0.f;

    for (int idx = beg; idx < end; ++idx) {
        int e = eid[idx];
        int s = srcArr[e];
        float ea = eattr[e];
        float2 xl2 = *(const float2*)(xl + (size_t)s * 128 + lane * 2);
        float mx = xl2.x + xr2.x + ea * we2.x;
        float my = xl2.y + xr2.y + ea * we2.y;
        mx = (mx > 0.f) ? mx : NEG_SLOPE * mx;
        my = (my > 0.f) ? my : NEG_SLOPE * my;
        float part = mx * att2.x + my * att2.y;
        #pragma unroll
        for (int off = 1; off < 64; off <<= 1)
            part += __shfl_xor(part, off);
        float mn = fmaxf(m_run, part);
        float sc = expf(m_run - mn);
        float p  = expf(part - mn);
        l_run = l_run * sc + p;
        accx  = accx * sc + p * xl2.x;
        accy  = accy * sc + p * xl2.y;
        m_run = mn;
    }

    float inv = (l_run > 0.f) ? 1.f / l_run : 0.f;
    float zx = fmaxf(accx * inv + bg2.x, 0.f);
    float zy = fmaxf(accy * inv + bg2.y, 0.f);
    half2v o; o.x = (_Float16)zx; o.y = (_Float16)zy;
    *(half2v*)(z + (size_t)node * 128 + lane * 2) = o;
}

// ---------------------------------------------------------------------------
// Decoder layer 2 + softmax, f32 out
// ---------------------------------------------------------------------------
__global__ __launch_bounds__(256)
void dec2_softmax_kernel(const float* __restrict__ d, const float* __restrict__ Wd2,
                         const float* __restrict__ bd2, float* __restrict__ out,
                         int n)
{
    __shared__ float wsm[64 * 10];
    __shared__ float bsm[10];
    const int t = threadIdx.x;
    for (int i = t; i < 640; i += 256) wsm[i] = Wd2[i];
    if (t < 10) bsm[t] = bd2[t];
    __syncthreads();

    int node = blockIdx.x * 256 + t;
    if (node >= n) return;

    const float* dr = d + (size_t)node * 64;
    float logits[10];
    #pragma unroll
    for (int c = 0; c < 10; ++c) logits[c] = bsm[c];
    for (int k = 0; k < 64; k += 4) {
        float4 dv = *(const float4*)(dr + k);
        #pragma unroll
        for (int c = 0; c < 10; ++c) {
            logits[c] += dv.x * wsm[(k + 0) * 10 + c];
            logits[c] += dv.y * wsm[(k + 1) * 10 + c];
            logits[c] += dv.z * wsm[(k + 2) * 10 + c];
            logits[c] += dv.w * wsm[(k + 3) * 10 + c];
        }
    }
    float mx = logits[0];
    #pragma unroll
    for (int c = 1; c < 10; ++c) mx = fmaxf(mx, logits[c]);
    float ssum = 0.f;
    #pragma unroll
    for (int c = 0; c < 10; ++c) { logits[c] = expf(logits[c] - mx); ssum += logits[c]; }
    float inv = 1.f / ssum;
    #pragma unroll
    for (int c = 0; c < 10; ++c)
        out[(size_t)node * 10 + c] = logits[c] * inv;
}

// ---------------------------------------------------------------------------
// Launch
// ---------------------------------------------------------------------------
extern "C" void kernel_launch(void* const* d_in, const int* in_sizes, int n_in,
                              void* d_out, int out_size, void* d_ws, size_t ws_size,
                              hipStream_t stream)
{
    const float* x    = (const float*)d_in[0];
    const float* pos  = (const float*)d_in[1];
    const int*   ei   = (const int*)d_in[2];
    const float* ea   = (const float*)d_in[3];
    const float* W1   = (const float*)d_in[4];
    const float* b1   = (const float*)d_in[5];
    const float* W2   = (const float*)d_in[6];
    const float* b2   = (const float*)d_in[7];
    const float* W3   = (const float*)d_in[8];
    const float* b3   = (const float*)d_in[9];
    const float* Wl   = (const float*)d_in[10];
    const float* bl   = (const float*)d_in[11];
    const float* Wr   = (const float*)d_in[12];
    const float* br   = (const float*)d_in[13];
    const float* We   = (const float*)d_in[14];
    const float* att  = (const float*)d_in[15];
    const float* bg   = (const float*)d_in[16];
    const float* Wd1  = (const float*)d_in[17];
    const float* bd1  = (const float*)d_in[18];
    const float* Wd2  = (const float*)d_in[19];
    const float* bd2  = (const float*)d_in[20];
    float* out = (float*)d_out;

    const int N = in_sizes[0] / 500;   // 50000
    const int E = in_sizes[2] / 2;     // 800000

    // ---- workspace layout (bytes) ----
    char* base = (char*)d_ws;
    const size_t szR = (size_t)N * 512 * 2;         // 51.2 MB region size
    // region 0: A0h -> later h2h, hh, zh, dd
    _Float16* A0h = (_Float16*)(base);                            // N*512 f16
    _Float16* h2h = (_Float16*)(base);                            // N*256 f16 (A0h dead)
    _Float16* hh  = (_Float16*)(base + (size_t)N * 256 * 2);      // N*128 f16
    _Float16* zh  = (_Float16*)(base + (size_t)N * 384 * 2);      // N*128 f16
    float*    dd  = (float*)(base);                               // N*64 f32 (h2h dead)
    // region 1: h1h -> later xl, xr
    char* r1 = base + szR;
    _Float16* h1h = (_Float16*)(r1);                              // N*512 f16
    float*    xl  = (float*)(r1);                                 // N*128 f32 (h1h dead)
    float*    xr  = (float*)(r1 + (size_t)N * 128 * 4);           // N*128 f32
    // region 2: weights + CSR
    char* r2 = base + 2 * szR;
    _Float16* W1t  = (_Float16*)(r2);                 // 512*512
    _Float16* W2t  = W1t  + 512 * 512;                // 256*512
    _Float16* W3t  = W2t  + 256 * 512;                // 128*256
    _Float16* Wlt  = W3t  + 128 * 256;                // 128*128
    _Float16* Wrt  = Wlt  + 128 * 128;                // 128*128
    _Float16* Wd1t = Wrt  + 128 * 128;                // 64*128
    int* cnt       = (int*)(r2 + 1 * 1024 * 1024);
    int* row_start = cnt + N;
    int* eid       = row_start + N + 1;

    const int* srcArr = ei;
    const int* dstArr = ei + E;
    const int gx = (N + 127) / 128;

    // ---- conversions ----
    concat_f16_kernel<<<2048, 256, 0, stream>>>(x, pos, A0h, N);
    wconv_kernel<<<1024, 256, 0, stream>>>(W1,  W1t,  502, 512, 512);
    wconv_kernel<<<512,  256, 0, stream>>>(W2,  W2t,  512, 256, 512);
    wconv_kernel<<<128,  256, 0, stream>>>(W3,  W3t,  256, 128, 256);
    wconv_kernel<<<64,   256, 0, stream>>>(Wl,  Wlt,  128, 128, 128);
    wconv_kernel<<<64,   256, 0, stream>>>(Wr,  Wrt,  128, 128, 128);
    wconv_kernel<<<32,   256, 0, stream>>>(Wd1, Wd1t, 128, 64,  128);

    // ---- CSR build (independent of GEMMs) ----
    init_cnt_kernel<<<256, 256, 0, stream>>>(cnt, N);
    count_edges_kernel<<<(E + 255) / 256, 256, 0, stream>>>(dstArr, cnt, E);
    scan_kernel<<<1, 1024, 0, stream>>>(cnt, row_start, cnt, N);
    scatter_edges_kernel<<<(E + 255) / 256, 256, 0, stream>>>(dstArr, cnt, eid, E);

    // ---- encoder ----
    gemm_f16_kernel<0,1><<<dim3(gx, 4), 256, 0, stream>>>(A0h, W1t, b1, nullptr, h1h, N, 512, 512, 1);
    gemm_f16_kernel<0,1><<<dim3(gx, 2), 256, 0, stream>>>(h1h, W2t, b2, nullptr, h2h, N, 256, 512, 1);
    gemm_f16_kernel<0,1><<<dim3(gx, 1), 256, 0, stream>>>(h2h, W3t, b3, nullptr, hh,  N, 128, 256, 0);
    // ---- GATv2 node transforms ----
    gemm_f16_kernel<1,0><<<dim3(gx, 1), 256, 0, stream>>>(hh, Wlt, bl, xl, nullptr, N, 128, 128, 0);
    gemm_f16_kernel<1,0><<<dim3(gx, 1), 256, 0, stream>>>(hh, Wrt, br, xr, nullptr, N, 128, 128, 0);

    // ---- fused GATv2 softmax + aggregation ----
    gat_aggregate_kernel<<<(N + 3) / 4, 256, 0, stream>>>(xl, xr, srcArr, ea, We, att, bg,
                                                          row_start, eid, zh, N);

    // ---- decoder ----
    gemm_f16_kernel<1,0><<<dim3(gx, 1), 256, 0, stream>>>(zh, Wd1t, bd1, dd, nullptr, N, 64, 128, 1);
    dec2_softmax_kernel<<<(N + 255) / 256, 256, 0, stream>>>(dd, Wd2, bd2, out, N);
}

// Round 4
// 418.654 us; speedup vs baseline: 3.0272x; 1.3659x over previous
//
#include <hip/hip_runtime.h>
#include <hip/hip_bf16.h>

// N=50000 nodes, E=800000 edges, D_IN=500, D_POS=2, LATENT=128, C=10
#define NEG_SLOPE 0.2f

typedef _Float16 half8  __attribute__((ext_vector_type(8)));
typedef _Float16 half2v __attribute__((ext_vector_type(2)));
typedef float   float4v __attribute__((ext_vector_type(4)));

// ---------------------------------------------------------------------------
// concat(x,pos) -> f16 [N x 512], cols 502..511 zero
// ---------------------------------------------------------------------------
__global__ __launch_bounds__(256)
void concat_f16_kernel(const float* __restrict__ x, const float* __restrict__ pos,
                       _Float16* __restrict__ A0, int N)
{
    const int total = N * 256;            // each thread: 2 consecutive cols
    for (int i = blockIdx.x * 256 + threadIdx.x; i < total; i += gridDim.x * 256) {
        int node = i >> 8;
        int c2   = (i & 255) * 2;
        float2 v = make_float2(0.f, 0.f);
        if (c2 < 500)       v = *(const float2*)(x + (size_t)node * 500 + c2);
        else if (c2 == 500) v = *(const float2*)(pos + (size_t)node * 2);
        half2v h; h.x = (_Float16)v.x; h.y = (_Float16)v.y;
        *(half2v*)(A0 + (size_t)node * 512 + c2) = h;
    }
}

// ---------------------------------------------------------------------------
// weight convert + transpose: W f32 [K x Nout] -> Wt f16 [Nout x Kpad]
// ---------------------------------------------------------------------------
__global__ void wconv_kernel(const float* __restrict__ W, _Float16* __restrict__ Wt,
                             int K, int Nout, int Kpad)
{
    int total = Nout * Kpad;
    for (int i = blockIdx.x * blockDim.x + threadIdx.x; i < total;
         i += gridDim.x * blockDim.x) {
        int n = i / Kpad, k = i - n * Kpad;
        Wt[i] = (_Float16)((k < K) ? W[(size_t)k * Nout + n] : 0.f);
    }
}

// ---------------------------------------------------------------------------
// f16 MFMA GEMM: 128x128 tile, BK=32, 4 waves (2x2), wave = 64x64 via 4x4
// mfma_f32_16x16x32_f16. LDS row pitch 40 f16.
// ---------------------------------------------------------------------------
template<int WF32, int WF16>
__global__ __launch_bounds__(256)
void gemm_f16_kernel(const _Float16* __restrict__ A, const _Float16* __restrict__ Bt,
                     const float* __restrict__ bias, float* __restrict__ Cf,
                     _Float16* __restrict__ Ch, int M, int N, int K, int do_relu)
{
    __shared__ __align__(16) _Float16 As[128 * 40];
    __shared__ __align__(16) _Float16 Bs[128 * 40];

    const int t    = threadIdx.x;
    const int row0 = blockIdx.x * 128;
    const int n0   = blockIdx.y * 128;
    const int K8   = K >> 3;
    const int lane = t & 63;
    const int w    = t >> 6;
    const int wrow = (w >> 1) * 64;
    const int wcol = (w & 1) * 64;
    const int lrow = lane & 15;
    const int lk   = lane >> 4;

    const int r0 = t >> 2;
    const int kq = t & 3;

    const uint4* Ag = (const uint4*)A;
    const uint4* Bg = (const uint4*)Bt;

    float4v acc[4][4];
    #pragma unroll
    for (int i = 0; i < 4; ++i)
        #pragma unroll
        for (int j = 0; j < 4; ++j)
            acc[i][j] = (float4v){0.f, 0.f, 0.f, 0.f};

    const int KT = K >> 5;
    uint4 ra[2], rb[2];

    auto load_tile = [&](int kt) {
        int kb = kt * 4;
        #pragma unroll
        for (int i = 0; i < 2; ++i) {
            int row = r0 + i * 64;
            int gr  = row0 + row;
            int gc  = n0 + row;
            uint4 za; za.x = za.y = za.z = za.w = 0u;
            uint4 zb; zb.x = zb.y = zb.z = zb.w = 0u;
            if (gr < M) za = Ag[(size_t)gr * K8 + kb + kq];
            if (gc < N) zb = Bg[(size_t)gc * K8 + kb + kq];
            ra[i] = za; rb[i] = zb;
        }
    };
    auto store_tile = [&]() {
        #pragma unroll
        for (int i = 0; i < 2; ++i) {
            int row = r0 + i * 64;
            *(uint4*)&As[row * 40 + kq * 8] = ra[i];
            *(uint4*)&Bs[row * 40 + kq * 8] = rb[i];
        }
    };

    load_tile(0);
    store_tile();
    __syncthreads();

    for (int kt = 0; kt < KT; ++kt) {
        if (kt + 1 < KT) load_tile(kt + 1);

        half8 af[4], bf[4];
        #pragma unroll
        for (int mi = 0; mi < 4; ++mi)
            af[mi] = *(const half8*)&As[(wrow + mi * 16 + lrow) * 40 + lk * 8];
        #pragma unroll
        for (int ni = 0; ni < 4; ++ni)
            bf[ni] = *(const half8*)&Bs[(wcol + ni * 16 + lrow) * 40 + lk * 8];

        #pragma unroll
        for (int mi = 0; mi < 4; ++mi)
            #pragma unroll
            for (int ni = 0; ni < 4; ++ni)
                acc[mi][ni] = __builtin_amdgcn_mfma_f32_16x16x32_f16(
                    af[mi], bf[ni], acc[mi][ni], 0, 0, 0);

        __syncthreads();
        if (kt + 1 < KT) { store_tile(); __syncthreads(); }
    }

    #pragma unroll
    for (int mi = 0; mi < 4; ++mi) {
        #pragma unroll
        for (int ni = 0; ni < 4; ++ni) {
            #pragma unroll
            for (int r = 0; r < 4; ++r) {
                int row = row0 + wrow + mi * 16 + lk * 4 + r;
                int col = n0 + wcol + ni * 16 + lrow;
                if (row < M && col < N) {
                    float v = acc[mi][ni][r] + bias[col];
                    if (do_relu) v = fmaxf(v, 0.f);
                    if (WF32) Cf[(size_t)row * N + col] = v;
                    if (WF16) Ch[(size_t)row * N + col] = (_Float16)v;
                }
            }
        }
    }
}

// ---------------------------------------------------------------------------
// CSR build: count -> hierarchical scan (3 small kernels) -> scatter
// ---------------------------------------------------------------------------
__global__ void init_cnt_kernel(int* cnt, int n)
{
    for (int i = blockIdx.x * blockDim.x + threadIdx.x; i < n;
         i += gridDim.x * blockDim.x)
        cnt[i] = 0;
}

__global__ void count_edges_kernel(const int* __restrict__ dst, int* cnt, int E)
{
    int e = blockIdx.x * blockDim.x + threadIdx.x;
    if (e < E) atomicAdd(&cnt[dst[e]], 1);
}

// per-block sum of 256 counts
__global__ __launch_bounds__(256)
void block_sum_kernel(const int* __restrict__ cnt, int* __restrict__ bsum, int n)
{
    __shared__ int sh[256];
    int t = threadIdx.x;
    int i = blockIdx.x * 256 + t;
    sh[t] = (i < n) ? cnt[i] : 0;
    __syncthreads();
    #pragma unroll
    for (int off = 128; off > 0; off >>= 1) {
        if (t < off) sh[t] += sh[t + off];
        __syncthreads();
    }
    if (t == 0) bsum[blockIdx.x] = sh[0];
}

// single block: exclusive scan of nb (<=256) block sums; row_start[n] = total
__global__ __launch_bounds__(256)
void scan_bsum_kernel(int* __restrict__ bsum, int* __restrict__ row_start, int nb, int n)
{
    __shared__ int sh[256];
    int t = threadIdx.x;
    int v = (t < nb) ? bsum[t] : 0;
    sh[t] = v;
    __syncthreads();
    #pragma unroll
    for (int off = 1; off < 256; off <<= 1) {
        int xv = (t >= off) ? sh[t - off] : 0;
        __syncthreads();
        sh[t] += xv;
        __syncthreads();
    }
    if (t < nb) bsum[t] = sh[t] - v;          // exclusive block offset
    if (t == 255) row_start[n] = sh[255];     // total
}

// per-block exclusive scan + block offset -> row_start, cursor
__global__ __launch_bounds__(256)
void scan_final_kernel(const int* __restrict__ cnt, const int* __restrict__ boff,
                       int* __restrict__ row_start, int* __restrict__ cursor, int n)
{
    __shared__ int sh[256];
    int t = threadIdx.x;
    int i = blockIdx.x * 256 + t;
    int v = (i < n) ? cnt[i] : 0;
    sh[t] = v;
    __syncthreads();
    #pragma unroll
    for (int off = 1; off < 256; off <<= 1) {
        int xv = (t >= off) ? sh[t - off] : 0;
        __syncthreads();
        sh[t] += xv;
        __syncthreads();
    }
    if (i < n) {
        int ex = boff[blockIdx.x] + sh[t] - v;
        row_start[i] = ex;
        cursor[i]    = ex;
    }
}

__global__ void scatter_edges_kernel(const int* __restrict__ dst, int* cursor,
                                     int* eid, int E)
{
    int e = blockIdx.x * blockDim.x + threadIdx.x;
    if (e < E) {
        int p = atomicAdd(&cursor[dst[e]], 1);
        eid[p] = e;
    }
}

// ---------------------------------------------------------------------------
// Fused GATv2: one wave per dst node; 4x16-lane groups process 4 edges
// concurrently, each lane owns 8 dims; per-group online softmax states merged
// at the end. z = relu(agg+bg) -> f16.
// ---------------------------------------------------------------------------
__global__ __launch_bounds__(256)
void gat_aggregate_kernel(const float* __restrict__ xl, const float* __restrict__ xr,
                          const int* __restrict__ srcArr, const float* __restrict__ eattr,
                          const float* __restrict__ We, const float* __restrict__ att,
                          const float* __restrict__ bg, const int* __restrict__ row_start,
                          const int* __restrict__ eid, _Float16* __restrict__ z, int n)
{
    const int wave = threadIdx.x >> 6;
    const int lane = threadIdx.x & 63;
    const int node = blockIdx.x * 4 + wave;
    if (node >= n) return;

    const int g  = lane >> 4;     // edge-slot group 0..3
    const int sl = lane & 15;     // sublane: owns dims [sl*8, sl*8+8)
    const int d0 = sl * 8;

    float4 at0 = *(const float4*)(att + d0);
    float4 at1 = *(const float4*)(att + d0 + 4);
    float4 we0 = *(const float4*)(We + d0);
    float4 we1 = *(const float4*)(We + d0 + 4);
    const float* xrp = xr + (size_t)node * 128 + d0;
    float4 xr0 = *(const float4*)xrp;
    float4 xr1 = *(const float4*)(xrp + 4);

    const int beg = row_start[node];
    const int end = row_start[node + 1];

    float m_run = -INFINITY;
    float l_run = 0.f;
    float acc[8];
    #pragma unroll
    for (int j = 0; j < 8; ++j) acc[j] = 0.f;

    for (int idx = beg + g; idx < end; idx += 4) {
        int e = eid[idx];
        int s = srcArr[e];
        float eav = eattr[e];
        const float* xp = xl + (size_t)s * 128 + d0;
        float4 x0 = *(const float4*)xp;
        float4 x1 = *(const float4*)(xp + 4);

        float mv[8] = {x0.x + xr0.x + eav * we0.x, x0.y + xr0.y + eav * we0.y,
                       x0.z + xr0.z + eav * we0.z, x0.w + xr0.w + eav * we0.w,
                       x1.x + xr1.x + eav * we1.x, x1.y + xr1.y + eav * we1.y,
                       x1.z + xr1.z + eav * we1.z, x1.w + xr1.w + eav * we1.w};
        float av[8] = {at0.x, at0.y, at0.z, at0.w, at1.x, at1.y, at1.z, at1.w};
        float xv[8] = {x0.x, x0.y, x0.z, x0.w, x1.x, x1.y, x1.z, x1.w};

        float part = 0.f;
        #pragma unroll
        for (int j = 0; j < 8; ++j) {
            float m = mv[j];
            m = (m > 0.f) ? m : NEG_SLOPE * m;
            part += m * av[j];
        }
        // reduce across the 16-lane group
        part += __shfl_xor(part, 1);
        part += __shfl_xor(part, 2);
        part += __shfl_xor(part, 4);
        part += __shfl_xor(part, 8);

        float mn = fmaxf(m_run, part);
        float sc = expf(m_run - mn);   // 0 on first iteration
        float p  = expf(part - mn);
        l_run = l_run * sc + p;
        #pragma unroll
        for (int j = 0; j < 8; ++j) acc[j] = acc[j] * sc + p * xv[j];
        m_run = mn;
    }

    // merge the 4 group states (xor 16, then 32)
    #pragma unroll
    for (int off = 16; off <= 32; off <<= 1) {
        float m_o = __shfl_xor(m_run, off);
        float l_o = __shfl_xor(l_run, off);
        float mn  = fmaxf(m_run, m_o);
        float sa  = expf(m_run - mn);
        float sb  = expf(m_o - mn);
        l_run = l_run * sa + l_o * sb;
        #pragma unroll
        for (int j = 0; j < 8; ++j) {
            float a_o = __shfl_xor(acc[j], off);
            acc[j] = acc[j] * sa + a_o * sb;
        }
        m_run = mn;
    }

    if (g == 0) {
        float inv = (l_run > 0.f) ? 1.f / l_run : 0.f;
        const float* bgp = bg + d0;
        half8 o;
        #pragma unroll
        for (int j = 0; j < 8; ++j) {
            float v = fmaxf(acc[j] * inv + bgp[j], 0.f);
            o[j] = (_Float16)v;
        }
        *(half8*)(z + (size_t)node * 128 + d0) = o;
    }
}

// ---------------------------------------------------------------------------
// Decoder layer 2 + softmax, f32 out
// ---------------------------------------------------------------------------
__global__ __launch_bounds__(256)
void dec2_softmax_kernel(const float* __restrict__ d, const float* __restrict__ Wd2,
                         const float* __restrict__ bd2, float* __restrict__ out,
                         int n)
{
    __shared__ float wsm[64 * 10];
    __shared__ float bsm[10];
    const int t = threadIdx.x;
    for (int i = t; i < 640; i += 256) wsm[i] = Wd2[i];
    if (t < 10) bsm[t] = bd2[t];
    __syncthreads();

    int node = blockIdx.x * 256 + t;
    if (node >= n) return;

    const float* dr = d + (size_t)node * 64;
    float logits[10];
    #pragma unroll
    for (int c = 0; c < 10; ++c) logits[c] = bsm[c];
    for (int k = 0; k < 64; k += 4) {
        float4 dv = *(const float4*)(dr + k);
        #pragma unroll
        for (int c = 0; c < 10; ++c) {
            logits[c] += dv.x * wsm[(k + 0) * 10 + c];
            logits[c] += dv.y * wsm[(k + 1) * 10 + c];
            logits[c] += dv.z * wsm[(k + 2) * 10 + c];
            logits[c] += dv.w * wsm[(k + 3) * 10 + c];
        }
    }
    float mx = logits[0];
    #pragma unroll
    for (int c = 1; c < 10; ++c) mx = fmaxf(mx, logits[c]);
    float ssum = 0.f;
    #pragma unroll
    for (int c = 0; c < 10; ++c) { logits[c] = expf(logits[c] - mx); ssum += logits[c]; }
    float inv = 1.f / ssum;
    #pragma unroll
    for (int c = 0; c < 10; ++c)
        out[(size_t)node * 10 + c] = logits[c] * inv;
}

// ---------------------------------------------------------------------------
// Launch
// ---------------------------------------------------------------------------
extern "C" void kernel_launch(void* const* d_in, const int* in_sizes, int n_in,
                              void* d_out, int out_size, void* d_ws, size_t ws_size,
                              hipStream_t stream)
{
    const float* x    = (const float*)d_in[0];
    const float* pos  = (const float*)d_in[1];
    const int*   ei   = (const int*)d_in[2];
    const float* ea   = (const float*)d_in[3];
    const float* W1   = (const float*)d_in[4];
    const float* b1   = (const float*)d_in[5];
    const float* W2   = (const float*)d_in[6];
    const float* b2   = (const float*)d_in[7];
    const float* W3   = (const float*)d_in[8];
    const float* b3   = (const float*)d_in[9];
    const float* Wl   = (const float*)d_in[10];
    const float* bl   = (const float*)d_in[11];
    const float* Wr   = (const float*)d_in[12];
    const float* br   = (const float*)d_in[13];
    const float* We   = (const float*)d_in[14];
    const float* att  = (const float*)d_in[15];
    const float* bg   = (const float*)d_in[16];
    const float* Wd1  = (const float*)d_in[17];
    const float* bd1  = (const float*)d_in[18];
    const float* Wd2  = (const float*)d_in[19];
    const float* bd2  = (const float*)d_in[20];
    float* out = (float*)d_out;

    const int N = in_sizes[0] / 500;   // 50000
    const int E = in_sizes[2] / 2;     // 800000

    // ---- workspace layout (bytes) ----
    char* base = (char*)d_ws;
    const size_t szR = (size_t)N * 512 * 2;         // 51.2 MB region size
    // region 0: A0h -> later h2h, hh, zh, dd
    _Float16* A0h = (_Float16*)(base);                            // N*512 f16
    _Float16* h2h = (_Float16*)(base);                            // N*256 f16 (A0h dead)
    _Float16* hh  = (_Float16*)(base + (size_t)N * 256 * 2);      // N*128 f16
    _Float16* zh  = (_Float16*)(base + (size_t)N * 384 * 2);      // N*128 f16
    float*    dd  = (float*)(base);                               // N*64 f32 (h2h dead)
    // region 1: h1h -> later xl, xr
    char* r1 = base + szR;
    _Float16* h1h = (_Float16*)(r1);                              // N*512 f16
    float*    xl  = (float*)(r1);                                 // N*128 f32 (h1h dead)
    float*    xr  = (float*)(r1 + (size_t)N * 128 * 4);           // N*128 f32
    // region 2: weights + CSR
    char* r2 = base + 2 * szR;
    _Float16* W1t  = (_Float16*)(r2);                 // 512*512
    _Float16* W2t  = W1t  + 512 * 512;                // 256*512
    _Float16* W3t  = W2t  + 256 * 512;                // 128*256
    _Float16* Wlt  = W3t  + 128 * 256;                // 128*128
    _Float16* Wrt  = Wlt  + 128 * 128;                // 128*128
    _Float16* Wd1t = Wrt  + 128 * 128;                // 64*128
    int* cnt       = (int*)(r2 + 1 * 1024 * 1024);
    int* row_start = cnt + N;
    int* eid       = row_start + N + 1;
    int* bsum      = eid + E;                         // ceil(N/256) ints

    const int* srcArr = ei;
    const int* dstArr = ei + E;
    const int gx = (N + 127) / 128;
    const int nb = (N + 255) / 256;                   // 196 blocks

    // ---- conversions ----
    concat_f16_kernel<<<2048, 256, 0, stream>>>(x, pos, A0h, N);
    wconv_kernel<<<1024, 256, 0, stream>>>(W1,  W1t,  502, 512, 512);
    wconv_kernel<<<512,  256, 0, stream>>>(W2,  W2t,  512, 256, 512);
    wconv_kernel<<<128,  256, 0, stream>>>(W3,  W3t,  256, 128, 256);
    wconv_kernel<<<64,   256, 0, stream>>>(Wl,  Wlt,  128, 128, 128);
    wconv_kernel<<<64,   256, 0, stream>>>(Wr,  Wrt,  128, 128, 128);
    wconv_kernel<<<32,   256, 0, stream>>>(Wd1, Wd1t, 128, 64,  128);

    // ---- CSR build ----
    init_cnt_kernel<<<256, 256, 0, stream>>>(cnt, N);
    count_edges_kernel<<<(E + 255) / 256, 256, 0, stream>>>(dstArr, cnt, E);
    block_sum_kernel<<<nb, 256, 0, stream>>>(cnt, bsum, N);
    scan_bsum_kernel<<<1, 256, 0, stream>>>(bsum, row_start, nb, N);
    scan_final_kernel<<<nb, 256, 0, stream>>>(cnt, bsum, row_start, cnt, N);
    scatter_edges_kernel<<<(E + 255) / 256, 256, 0, stream>>>(dstArr, cnt, eid, E);

    // ---- encoder ----
    gemm_f16_kernel<0,1><<<dim3(gx, 4), 256, 0, stream>>>(A0h, W1t, b1, nullptr, h1h, N, 512, 512, 1);
    gemm_f16_kernel<0,1><<<dim3(gx, 2), 256, 0, stream>>>(h1h, W2t, b2, nullptr, h2h, N, 256, 512, 1);
    gemm_f16_kernel<0,1><<<dim3(gx, 1), 256, 0, stream>>>(h2h, W3t, b3, nullptr, hh,  N, 128, 256, 0);
    // ---- GATv2 node transforms ----
    gemm_f16_kernel<1,0><<<dim3(gx, 1), 256, 0, stream>>>(hh, Wlt, bl, xl, nullptr, N, 128, 128, 0);
    gemm_f16_kernel<1,0><<<dim3(gx, 1), 256, 0, stream>>>(hh, Wrt, br, xr, nullptr, N, 128, 128, 0);

    // ---- fused GATv2 softmax + aggregation ----
    gat_aggregate_kernel<<<(N + 3) / 4, 256, 0, stream>>>(xl, xr, srcArr, ea, We, att, bg,
                                                          row_start, eid, zh, N);

    // ---- decoder ----
    gemm_f16_kernel<1,0><<<dim3(gx, 1), 256, 0, stream>>>(zh, Wd1t, bd1, dd, nullptr, N, 64, 128, 1);
    dec2_softmax_kernel<<<(N + 255) / 256, 256, 0, stream>>>(dd, Wd2, bd2, out, N);
}

// Round 5
// 415.542 us; speedup vs baseline: 3.0499x; 1.0075x over previous
//
#include <hip/hip_runtime.h>
#include <hip/hip_bf16.h>

// N=50000 nodes, E=800000 edges, D_IN=500, D_POS=2, LATENT=128, C=10
#define NEG_SLOPE 0.2f

typedef _Float16 half8  __attribute__((ext_vector_type(8)));
typedef float   float4v __attribute__((ext_vector_type(4)));

// ---------------------------------------------------------------------------
// weight convert + transpose: W f32 [K x Nout] -> Wt f16 [Nout x Kpad]
// ---------------------------------------------------------------------------
__global__ void wconv_kernel(const float* __restrict__ W, _Float16* __restrict__ Wt,
                             int K, int Nout, int Kpad)
{
    int total = Nout * Kpad;
    for (int i = blockIdx.x * blockDim.x + threadIdx.x; i < total;
         i += gridDim.x * blockDim.x) {
        int n = i / Kpad, k = i - n * Kpad;
        Wt[i] = (_Float16)((k < K) ? W[(size_t)k * Nout + n] : 0.f);
    }
}

// combined [Wl|Wr] -> Wt f16 [256 x 128], bias_lr f32 [256]
__global__ void wconv_lr_kernel(const float* __restrict__ Wl, const float* __restrict__ Wr,
                                const float* __restrict__ bl, const float* __restrict__ br,
                                _Float16* __restrict__ Wt, float* __restrict__ bias_lr)
{
    int i0 = blockIdx.x * blockDim.x + threadIdx.x;
    if (i0 < 256) bias_lr[i0] = (i0 < 128) ? bl[i0] : br[i0 - 128];
    for (int i = i0; i < 256 * 128; i += gridDim.x * blockDim.x) {
        int n = i >> 7, k = i & 127;
        const float* Ws = (n < 128) ? Wl : Wr;
        Wt[i] = (_Float16)Ws[(size_t)k * 128 + (n & 127)];
    }
}

// ---------------------------------------------------------------------------
// f16 MFMA GEMM: 128x128 tile, BK=32, 4 waves (2x2), wave = 64x64 via 4x4
// mfma_f32_16x16x32_f16. LDS row pitch 40 f16.
// CONCAT=1: A-operand is concat(x[N,500] f32, pos[N,2] f32, zero-pad to 512),
// converted to f16 during LDS staging.
// ---------------------------------------------------------------------------
template<int CONCAT, int WF32, int WF16>
__global__ __launch_bounds__(256)
void gemm_f16_kernel(const _Float16* __restrict__ A,
                     const float* __restrict__ xf, const float* __restrict__ posf,
                     const _Float16* __restrict__ Bt,
                     const float* __restrict__ bias, float* __restrict__ Cf,
                     _Float16* __restrict__ Ch, int M, int N, int K, int do_relu)
{
    __shared__ __align__(16) _Float16 As[128 * 40];
    __shared__ __align__(16) _Float16 Bs[128 * 40];

    const int t    = threadIdx.x;
    const int row0 = blockIdx.x * 128;
    const int n0   = blockIdx.y * 128;
    const int lane = t & 63;
    const int w    = t >> 6;
    const int wrow = (w >> 1) * 64;
    const int wcol = (w & 1) * 64;
    const int lrow = lane & 15;
    const int lk   = lane >> 4;

    const int r0 = t >> 2;
    const int kq = t & 3;

    float4v acc[4][4];
    #pragma unroll
    for (int i = 0; i < 4; ++i)
        #pragma unroll
        for (int j = 0; j < 4; ++j)
            acc[i][j] = (float4v){0.f, 0.f, 0.f, 0.f};

    const int KT = K >> 5;
    half8 ra[2], rb[2];

    auto load_tile = [&](int kt) {
        int kb = kt * 32 + kq * 8;
        #pragma unroll
        for (int i = 0; i < 2; ++i) {
            int row = r0 + i * 64;
            int gr  = row0 + row;
            int gc  = n0 + row;
            half8 ha; half8 hb;
            #pragma unroll
            for (int j = 0; j < 8; ++j) { ha[j] = (_Float16)0.f; hb[j] = (_Float16)0.f; }
            if (CONCAT) {
                if (gr < M) {
                    if (kb + 7 < 500) {
                        float4 a = *(const float4*)(xf + (size_t)gr * 500 + kb);
                        float4 b = *(const float4*)(xf + (size_t)gr * 500 + kb + 4);
                        ha[0] = (_Float16)a.x; ha[1] = (_Float16)a.y;
                        ha[2] = (_Float16)a.z; ha[3] = (_Float16)a.w;
                        ha[4] = (_Float16)b.x; ha[5] = (_Float16)b.y;
                        ha[6] = (_Float16)b.z; ha[7] = (_Float16)b.w;
                    } else {
                        #pragma unroll
                        for (int j = 0; j < 8; ++j) {
                            int k = kb + j;
                            float v = 0.f;
                            if (k < 500)      v = xf[(size_t)gr * 500 + k];
                            else if (k < 502) v = posf[(size_t)gr * 2 + (k - 500)];
                            ha[j] = (_Float16)v;
                        }
                    }
                }
            } else {
                if (gr < M) ha = *(const half8*)(A + (size_t)gr * K + kb);
            }
            if (gc < N) hb = *(const half8*)(Bt + (size_t)gc * K + kb);
            ra[i] = ha; rb[i] = hb;
        }
    };
    auto store_tile = [&]() {
        #pragma unroll
        for (int i = 0; i < 2; ++i) {
            int row = r0 + i * 64;
            *(half8*)&As[row * 40 + kq * 8] = ra[i];
            *(half8*)&Bs[row * 40 + kq * 8] = rb[i];
        }
    };

    load_tile(0);
    store_tile();
    __syncthreads();

    for (int kt = 0; kt < KT; ++kt) {
        if (kt + 1 < KT) load_tile(kt + 1);

        half8 af[4], bf[4];
        #pragma unroll
        for (int mi = 0; mi < 4; ++mi)
            af[mi] = *(const half8*)&As[(wrow + mi * 16 + lrow) * 40 + lk * 8];
        #pragma unroll
        for (int ni = 0; ni < 4; ++ni)
            bf[ni] = *(const half8*)&Bs[(wcol + ni * 16 + lrow) * 40 + lk * 8];

        #pragma unroll
        for (int mi = 0; mi < 4; ++mi)
            #pragma unroll
            for (int ni = 0; ni < 4; ++ni)
                acc[mi][ni] = __builtin_amdgcn_mfma_f32_16x16x32_f16(
                    af[mi], bf[ni], acc[mi][ni], 0, 0, 0);

        __syncthreads();
        if (kt + 1 < KT) { store_tile(); __syncthreads(); }
    }

    #pragma unroll
    for (int mi = 0; mi < 4; ++mi) {
        #pragma unroll
        for (int ni = 0; ni < 4; ++ni) {
            #pragma unroll
            for (int r = 0; r < 4; ++r) {
                int row = row0 + wrow + mi * 16 + lk * 4 + r;
                int col = n0 + wcol + ni * 16 + lrow;
                if (row < M && col < N) {
                    float v = acc[mi][ni][r] + bias[col];
                    if (do_relu) v = fmaxf(v, 0.f);
                    if (WF32) Cf[(size_t)row * N + col] = v;
                    if (WF16) Ch[(size_t)row * N + col] = (_Float16)v;
                }
            }
        }
    }
}

// ---------------------------------------------------------------------------
// CSR build: count -> hierarchical scan -> scatter (src, ea) records
// ---------------------------------------------------------------------------
__global__ void init_cnt_kernel(int* cnt, int n)
{
    for (int i = blockIdx.x * blockDim.x + threadIdx.x; i < n;
         i += gridDim.x * blockDim.x)
        cnt[i] = 0;
}

__global__ void count_edges_kernel(const int* __restrict__ dst, int* cnt, int E)
{
    int e = blockIdx.x * blockDim.x + threadIdx.x;
    if (e < E) atomicAdd(&cnt[dst[e]], 1);
}

__global__ __launch_bounds__(256)
void block_sum_kernel(const int* __restrict__ cnt, int* __restrict__ bsum, int n)
{
    __shared__ int sh[256];
    int t = threadIdx.x;
    int i = blockIdx.x * 256 + t;
    sh[t] = (i < n) ? cnt[i] : 0;
    __syncthreads();
    #pragma unroll
    for (int off = 128; off > 0; off >>= 1) {
        if (t < off) sh[t] += sh[t + off];
        __syncthreads();
    }
    if (t == 0) bsum[blockIdx.x] = sh[0];
}

__global__ __launch_bounds__(256)
void scan_bsum_kernel(int* __restrict__ bsum, int* __restrict__ row_start, int nb, int n)
{
    __shared__ int sh[256];
    int t = threadIdx.x;
    int v = (t < nb) ? bsum[t] : 0;
    sh[t] = v;
    __syncthreads();
    #pragma unroll
    for (int off = 1; off < 256; off <<= 1) {
        int xv = (t >= off) ? sh[t - off] : 0;
        __syncthreads();
        sh[t] += xv;
        __syncthreads();
    }
    if (t < nb) bsum[t] = sh[t] - v;
    if (t == 255) row_start[n] = sh[255];
}

__global__ __launch_bounds__(256)
void scan_final_kernel(const int* __restrict__ cnt, const int* __restrict__ boff,
                       int* __restrict__ row_start, int* __restrict__ cursor, int n)
{
    __shared__ int sh[256];
    int t = threadIdx.x;
    int i = blockIdx.x * 256 + t;
    int v = (i < n) ? cnt[i] : 0;
    sh[t] = v;
    __syncthreads();
    #pragma unroll
    for (int off = 1; off < 256; off <<= 1) {
        int xv = (t >= off) ? sh[t - off] : 0;
        __syncthreads();
        sh[t] += xv;
        __syncthreads();
    }
    if (i < n) {
        int ex = boff[blockIdx.x] + sh[t] - v;
        row_start[i] = ex;
        cursor[i]    = ex;
    }
}

__global__ void scatter_edges_kernel(const int* __restrict__ dst, const int* __restrict__ src,
                                     const float* __restrict__ ea, int* cursor,
                                     int2* __restrict__ recs, int E)
{
    int e = blockIdx.x * blockDim.x + threadIdx.x;
    if (e < E) {
        int p = atomicAdd(&cursor[dst[e]], 1);
        recs[p] = make_int2(src[e], __float_as_int(ea[e]));
    }
}

// ---------------------------------------------------------------------------
// Fused GATv2: one wave per dst node; 4x16-lane groups process 4 edges
// concurrently; lane owns 8 dims (f16 xlr rows: [xl|xr] 256 f16 per node).
// ---------------------------------------------------------------------------
__global__ __launch_bounds__(256)
void gat_aggregate_kernel(const _Float16* __restrict__ xlr, const int2* __restrict__ recs,
                          const float* __restrict__ We, const float* __restrict__ att,
                          const float* __restrict__ bg, const int* __restrict__ row_start,
                          _Float16* __restrict__ z, int n)
{
    const int wave = threadIdx.x >> 6;
    const int lane = threadIdx.x & 63;
    const int node = blockIdx.x * 4 + wave;
    if (node >= n) return;

    const int g  = lane >> 4;
    const int sl = lane & 15;
    const int d0 = sl * 8;

    float at8[8], we8[8], xr8[8];
    {
        float4 a0 = *(const float4*)(att + d0);
        float4 a1 = *(const float4*)(att + d0 + 4);
        float4 w0 = *(const float4*)(We + d0);
        float4 w1 = *(const float4*)(We + d0 + 4);
        at8[0]=a0.x; at8[1]=a0.y; at8[2]=a0.z; at8[3]=a0.w;
        at8[4]=a1.x; at8[5]=a1.y; at8[6]=a1.z; at8[7]=a1.w;
        we8[0]=w0.x; we8[1]=w0.y; we8[2]=w0.z; we8[3]=w0.w;
        we8[4]=w1.x; we8[5]=w1.y; we8[6]=w1.z; we8[7]=w1.w;
        half8 xh = *(const half8*)(xlr + (size_t)node * 256 + 128 + d0);
        #pragma unroll
        for (int j = 0; j < 8; ++j) xr8[j] = (float)xh[j];
    }

    const int beg = row_start[node];
    const int end = row_start[node + 1];

    float m_run = -INFINITY;
    float l_run = 0.f;
    float acc[8];
    #pragma unroll
    for (int j = 0; j < 8; ++j) acc[j] = 0.f;

    for (int idx = beg + g; idx < end; idx += 4) {
        int2 rec  = recs[idx];
        float eav = __int_as_float(rec.y);
        half8 xh  = *(const half8*)(xlr + (size_t)rec.x * 256 + d0);

        float part = 0.f;
        float xv[8];
        #pragma unroll
        for (int j = 0; j < 8; ++j) {
            float xj = (float)xh[j];
            xv[j] = xj;
            float m = xj + xr8[j] + eav * we8[j];
            m = (m > 0.f) ? m : NEG_SLOPE * m;
            part += m * at8[j];
        }
        part += __shfl_xor(part, 1);
        part += __shfl_xor(part, 2);
        part += __shfl_xor(part, 4);
        part += __shfl_xor(part, 8);

        float mn = fmaxf(m_run, part);
        float sc = expf(m_run - mn);   // 0 on first iteration (m_run=-inf, mn finite)
        float p  = expf(part - mn);
        l_run = l_run * sc + p;
        #pragma unroll
        for (int j = 0; j < 8; ++j) acc[j] = acc[j] * sc + p * xv[j];
        m_run = mn;
    }

    // merge the 4 group states; guard scale=1 when m==mn (handles empty/empty)
    #pragma unroll
    for (int off = 16; off <= 32; off <<= 1) {
        float m_o = __shfl_xor(m_run, off);
        float l_o = __shfl_xor(l_run, off);
        float mn  = fmaxf(m_run, m_o);
        float sa  = (m_run == mn) ? 1.f : expf(m_run - mn);
        float sb  = (m_o   == mn) ? 1.f : expf(m_o - mn);
        l_run = l_run * sa + l_o * sb;
        #pragma unroll
        for (int j = 0; j < 8; ++j) {
            float a_o = __shfl_xor(acc[j], off);
            acc[j] = acc[j] * sa + a_o * sb;
        }
        m_run = mn;
    }

    if (g == 0) {
        float inv = (l_run > 0.f) ? 1.f / l_run : 0.f;
        const float* bgp = bg + d0;
        half8 o;
        #pragma unroll
        for (int j = 0; j < 8; ++j) {
            float v = fmaxf(acc[j] * inv + bgp[j], 0.f);
            o[j] = (_Float16)v;
        }
        *(half8*)(z + (size_t)node * 128 + d0) = o;
    }
}

// ---------------------------------------------------------------------------
// Decoder layer 2 + softmax, f32 out
// ---------------------------------------------------------------------------
__global__ __launch_bounds__(256)
void dec2_softmax_kernel(const float* __restrict__ d, const float* __restrict__ Wd2,
                         const float* __restrict__ bd2, float* __restrict__ out,
                         int n)
{
    __shared__ float wsm[64 * 10];
    __shared__ float bsm[10];
    const int t = threadIdx.x;
    for (int i = t; i < 640; i += 256) wsm[i] = Wd2[i];
    if (t < 10) bsm[t] = bd2[t];
    __syncthreads();

    int node = blockIdx.x * 256 + t;
    if (node >= n) return;

    const float* dr = d + (size_t)node * 64;
    float logits[10];
    #pragma unroll
    for (int c = 0; c < 10; ++c) logits[c] = bsm[c];
    for (int k = 0; k < 64; k += 4) {
        float4 dv = *(const float4*)(dr + k);
        #pragma unroll
        for (int c = 0; c < 10; ++c) {
            logits[c] += dv.x * wsm[(k + 0) * 10 + c];
            logits[c] += dv.y * wsm[(k + 1) * 10 + c];
            logits[c] += dv.z * wsm[(k + 2) * 10 + c];
            logits[c] += dv.w * wsm[(k + 3) * 10 + c];
        }
    }
    float mx = logits[0];
    #pragma unroll
    for (int c = 1; c < 10; ++c) mx = fmaxf(mx, logits[c]);
    float ssum = 0.f;
    #pragma unroll
    for (int c = 0; c < 10; ++c) { logits[c] = expf(logits[c] - mx); ssum += logits[c]; }
    float inv = 1.f / ssum;
    #pragma unroll
    for (int c = 0; c < 10; ++c)
        out[(size_t)node * 10 + c] = logits[c] * inv;
}

// ---------------------------------------------------------------------------
// Launch
// ---------------------------------------------------------------------------
extern "C" void kernel_launch(void* const* d_in, const int* in_sizes, int n_in,
                              void* d_out, int out_size, void* d_ws, size_t ws_size,
                              hipStream_t stream)
{
    const float* x    = (const float*)d_in[0];
    const float* pos  = (const float*)d_in[1];
    const int*   ei   = (const int*)d_in[2];
    const float* ea   = (const float*)d_in[3];
    const float* W1   = (const float*)d_in[4];
    const float* b1   = (const float*)d_in[5];
    const float* W2   = (const float*)d_in[6];
    const float* b2   = (const float*)d_in[7];
    const float* W3   = (const float*)d_in[8];
    const float* b3   = (const float*)d_in[9];
    const float* Wl   = (const float*)d_in[10];
    const float* bl   = (const float*)d_in[11];
    const float* Wr   = (const float*)d_in[12];
    const float* br   = (const float*)d_in[13];
    const float* We   = (const float*)d_in[14];
    const float* att  = (const float*)d_in[15];
    const float* bg   = (const float*)d_in[16];
    const float* Wd1  = (const float*)d_in[17];
    const float* bd1  = (const float*)d_in[18];
    const float* Wd2  = (const float*)d_in[19];
    const float* bd2  = (const float*)d_in[20];
    float* out = (float*)d_out;

    const int N = in_sizes[0] / 500;   // 50000
    const int E = in_sizes[2] / 2;     // 800000

    // ---- workspace layout (bytes) ----
    char* base = (char*)d_ws;
    const size_t szR = (size_t)N * 512 * 2;   // 51.2 MB region size
    // region 0: h2h -> hh, zh; dd reuses h2h space later
    _Float16* h2h = (_Float16*)(base);                            // N*256 f16
    _Float16* hh  = (_Float16*)(base + (size_t)N * 256 * 2);      // N*128 f16
    _Float16* zh  = (_Float16*)(base + (size_t)N * 384 * 2);      // N*128 f16
    float*    dd  = (float*)(base);                               // N*64 f32 (h2h dead)
    // region 1: h1h -> xlr
    char* r1 = base + szR;
    _Float16* h1h = (_Float16*)(r1);                              // N*512 f16
    _Float16* xlr = (_Float16*)(r1);                              // N*256 f16 (h1h dead)
    // region 2: weights + CSR
    char* r2 = base + 2 * szR;
    _Float16* W1t   = (_Float16*)(r2);                // 512*512
    _Float16* W2t   = W1t  + 512 * 512;               // 256*512
    _Float16* W3t   = W2t  + 256 * 512;               // 128*256
    _Float16* Wlrt  = W3t  + 128 * 256;               // 256*128
    _Float16* Wd1t  = Wlrt + 256 * 128;               // 64*128
    float*    blr   = (float*)(Wd1t + 64 * 128);      // 256 f32
    int* cnt       = (int*)(r2 + 2 * 1024 * 1024);
    int* row_start = cnt + N;
    int* bsum      = row_start + N + 1;
    int2* recs     = (int2*)(r2 + 3 * 1024 * 1024);   // E * 8 bytes

    const int* srcArr = ei;
    const int* dstArr = ei + E;
    const int gx = (N + 127) / 128;
    const int nb = (N + 255) / 256;

    // ---- weight conversions ----
    wconv_kernel<<<1024, 256, 0, stream>>>(W1,  W1t,  502, 512, 512);
    wconv_kernel<<<512,  256, 0, stream>>>(W2,  W2t,  512, 256, 512);
    wconv_kernel<<<128,  256, 0, stream>>>(W3,  W3t,  256, 128, 256);
    wconv_lr_kernel<<<128, 256, 0, stream>>>(Wl, Wr, bl, br, Wlrt, blr);
    wconv_kernel<<<32,   256, 0, stream>>>(Wd1, Wd1t, 128, 64,  128);

    // ---- CSR build ----
    init_cnt_kernel<<<256, 256, 0, stream>>>(cnt, N);
    count_edges_kernel<<<(E + 255) / 256, 256, 0, stream>>>(dstArr, cnt, E);
    block_sum_kernel<<<nb, 256, 0, stream>>>(cnt, bsum, N);
    scan_bsum_kernel<<<1, 256, 0, stream>>>(bsum, row_start, nb, N);
    scan_final_kernel<<<nb, 256, 0, stream>>>(cnt, bsum, row_start, cnt, N);
    scatter_edges_kernel<<<(E + 255) / 256, 256, 0, stream>>>(dstArr, srcArr, ea, cnt, recs, E);

    // ---- encoder (concat fused into GEMM-1 staging) ----
    gemm_f16_kernel<1,0,1><<<dim3(gx, 4), 256, 0, stream>>>(nullptr, x, pos, W1t, b1, nullptr, h1h, N, 512, 512, 1);
    gemm_f16_kernel<0,0,1><<<dim3(gx, 2), 256, 0, stream>>>(h1h, nullptr, nullptr, W2t, b2, nullptr, h2h, N, 256, 512, 1);
    gemm_f16_kernel<0,0,1><<<dim3(gx, 1), 256, 0, stream>>>(h2h, nullptr, nullptr, W3t, b3, nullptr, hh,  N, 128, 256, 0);
    // ---- combined xl|xr transform -> xlr f16 ----
    gemm_f16_kernel<0,0,1><<<dim3(gx, 2), 256, 0, stream>>>(hh, nullptr, nullptr, Wlrt, blr, nullptr, xlr, N, 256, 128, 0);

    // ---- fused GATv2 softmax + aggregation ----
    gat_aggregate_kernel<<<(N + 3) / 4, 256, 0, stream>>>(xlr, recs, We, att, bg,
                                                          row_start, zh, N);

    // ---- decoder ----
    gemm_f16_kernel<0,1,0><<<dim3(gx, 1), 256, 0, stream>>>(zh, nullptr, nullptr, Wd1t, bd1, dd, nullptr, N, 64, 128, 1);
    dec2_softmax_kernel<<<(N + 255) / 256, 256, 0, stream>>>(dd, Wd2, bd2, out, N);
}

// Round 6
// 381.425 us; speedup vs baseline: 3.3227x; 1.0894x over previous
//
#include <hip/hip_runtime.h>
#include <hip/hip_bf16.h>

// N=50000 nodes, E=800000 edges, D_IN=500, D_POS=2, LATENT=128, C=10
#define NEG_SLOPE 0.2f

typedef _Float16 half8  __attribute__((ext_vector_type(8)));
typedef _Float16 half2v __attribute__((ext_vector_type(2)));
typedef float   float4v __attribute__((ext_vector_type(4)));

// ---------------------------------------------------------------------------
// concat(x,pos) -> f16 [N x 512], cols 502..511 zero
// ---------------------------------------------------------------------------
__global__ __launch_bounds__(256)
void concat_f16_kernel(const float* __restrict__ x, const float* __restrict__ pos,
                       _Float16* __restrict__ A0, int N)
{
    const int total = N * 256;            // each thread: 2 consecutive cols
    for (int i = blockIdx.x * 256 + threadIdx.x; i < total; i += gridDim.x * 256) {
        int node = i >> 8;
        int c2   = (i & 255) * 2;
        float2 v = make_float2(0.f, 0.f);
        if (c2 < 500)       v = *(const float2*)(x + (size_t)node * 500 + c2);
        else if (c2 == 500) v = *(const float2*)(pos + (size_t)node * 2);
        half2v h; h.x = (_Float16)v.x; h.y = (_Float16)v.y;
        *(half2v*)(A0 + (size_t)node * 512 + c2) = h;
    }
}

// ---------------------------------------------------------------------------
// weight convert + transpose: W f32 [K x Nout] -> Wt f16 [Nout x Kpad]
// ---------------------------------------------------------------------------
__global__ void wconv_kernel(const float* __restrict__ W, _Float16* __restrict__ Wt,
                             int K, int Nout, int Kpad)
{
    int total = Nout * Kpad;
    for (int i = blockIdx.x * blockDim.x + threadIdx.x; i < total;
         i += gridDim.x * blockDim.x) {
        int n = i / Kpad, k = i - n * Kpad;
        Wt[i] = (_Float16)((k < K) ? W[(size_t)k * Nout + n] : 0.f);
    }
}

// combined [Wl|Wr] -> Wt f16 [256 x 128], bias_lr f32 [256]
__global__ void wconv_lr_kernel(const float* __restrict__ Wl, const float* __restrict__ Wr,
                                const float* __restrict__ bl, const float* __restrict__ br,
                                _Float16* __restrict__ Wt, float* __restrict__ bias_lr)
{
    int i0 = blockIdx.x * blockDim.x + threadIdx.x;
    if (i0 < 256) bias_lr[i0] = (i0 < 128) ? bl[i0] : br[i0 - 128];
    for (int i = i0; i < 256 * 128; i += gridDim.x * blockDim.x) {
        int n = i >> 7, k = i & 127;
        const float* Ws = (n < 128) ? Wl : Wr;
        Wt[i] = (_Float16)Ws[(size_t)k * 128 + (n & 127)];
    }
}

// ---------------------------------------------------------------------------
// XCD-aware bijective swizzle (m204): blocks in one XCD get a contiguous
// logical range; with col-blocks fastest in L, the ny col-blocks sharing one
// A row-panel run on the same XCD -> panel reads hit that XCD's L2.
// ---------------------------------------------------------------------------
__device__ inline void decode_swz(int b, int nblk, int ny, int& bx, int& by)
{
    int q = nblk >> 3, r = nblk & 7;
    int xcd = b & 7, j = b >> 3;
    int L = (xcd < r ? xcd * (q + 1) : r * (q + 1) + (xcd - r) * q) + j;
    bx = L / ny;
    by = L - bx * ny;
}

// ---------------------------------------------------------------------------
// f16 MFMA GEMM: 128x128 tile, BK=32, 4 waves (2x2), wave = 64x64 via 4x4
// mfma_f32_16x16x32_f16. LDS row pitch 40 f16. 1D grid + XCD swizzle.
// ---------------------------------------------------------------------------
template<int WF32, int WF16>
__global__ __launch_bounds__(256)
void gemm_f16_kernel(const _Float16* __restrict__ A, const _Float16* __restrict__ Bt,
                     const float* __restrict__ bias, float* __restrict__ Cf,
                     _Float16* __restrict__ Ch, int M, int N, int K, int ny, int do_relu)
{
    __shared__ __align__(16) _Float16 As[128 * 40];
    __shared__ __align__(16) _Float16 Bs[128 * 40];

    int bx, by;
    decode_swz(blockIdx.x, gridDim.x, ny, bx, by);

    const int t    = threadIdx.x;
    const int row0 = bx * 128;
    const int n0   = by * 128;
    const int lane = t & 63;
    const int w    = t >> 6;
    const int wrow = (w >> 1) * 64;
    const int wcol = (w & 1) * 64;
    const int lrow = lane & 15;
    const int lk   = lane >> 4;

    const int r0 = t >> 2;
    const int kq = t & 3;

    float4v acc[4][4];
    #pragma unroll
    for (int i = 0; i < 4; ++i)
        #pragma unroll
        for (int j = 0; j < 4; ++j)
            acc[i][j] = (float4v){0.f, 0.f, 0.f, 0.f};

    const int KT = K >> 5;
    half8 ra[2], rb[2];

    auto load_tile = [&](int kt) {
        int kb = kt * 32 + kq * 8;
        #pragma unroll
        for (int i = 0; i < 2; ++i) {
            int row = r0 + i * 64;
            int gr  = row0 + row;
            int gc  = n0 + row;
            half8 ha; half8 hb;
            #pragma unroll
            for (int j = 0; j < 8; ++j) { ha[j] = (_Float16)0.f; hb[j] = (_Float16)0.f; }
            if (gr < M) ha = *(const half8*)(A + (size_t)gr * K + kb);
            if (gc < N) hb = *(const half8*)(Bt + (size_t)gc * K + kb);
            ra[i] = ha; rb[i] = hb;
        }
    };
    auto store_tile = [&]() {
        #pragma unroll
        for (int i = 0; i < 2; ++i) {
            int row = r0 + i * 64;
            *(half8*)&As[row * 40 + kq * 8] = ra[i];
            *(half8*)&Bs[row * 40 + kq * 8] = rb[i];
        }
    };

    load_tile(0);
    store_tile();
    __syncthreads();

    for (int kt = 0; kt < KT; ++kt) {
        if (kt + 1 < KT) load_tile(kt + 1);

        half8 af[4], bf[4];
        #pragma unroll
        for (int mi = 0; mi < 4; ++mi)
            af[mi] = *(const half8*)&As[(wrow + mi * 16 + lrow) * 40 + lk * 8];
        #pragma unroll
        for (int ni = 0; ni < 4; ++ni)
            bf[ni] = *(const half8*)&Bs[(wcol + ni * 16 + lrow) * 40 + lk * 8];

        #pragma unroll
        for (int mi = 0; mi < 4; ++mi)
            #pragma unroll
            for (int ni = 0; ni < 4; ++ni)
                acc[mi][ni] = __builtin_amdgcn_mfma_f32_16x16x32_f16(
                    af[mi], bf[ni], acc[mi][ni], 0, 0, 0);

        __syncthreads();
        if (kt + 1 < KT) { store_tile(); __syncthreads(); }
    }

    #pragma unroll
    for (int mi = 0; mi < 4; ++mi) {
        #pragma unroll
        for (int ni = 0; ni < 4; ++ni) {
            #pragma unroll
            for (int r = 0; r < 4; ++r) {
                int row = row0 + wrow + mi * 16 + lk * 4 + r;
                int col = n0 + wcol + ni * 16 + lrow;
                if (row < M && col < N) {
                    float v = acc[mi][ni][r] + bias[col];
                    if (do_relu) v = fmaxf(v, 0.f);
                    if (WF32) Cf[(size_t)row * N + col] = v;
                    if (WF16) Ch[(size_t)row * N + col] = (_Float16)v;
                }
            }
        }
    }
}

// ---------------------------------------------------------------------------
// CSR build: count -> hierarchical scan -> scatter (src, ea) records
// ---------------------------------------------------------------------------
__global__ void init_cnt_kernel(int* cnt, int n)
{
    for (int i = blockIdx.x * blockDim.x + threadIdx.x; i < n;
         i += gridDim.x * blockDim.x)
        cnt[i] = 0;
}

__global__ void count_edges_kernel(const int* __restrict__ dst, int* cnt, int E)
{
    int e = blockIdx.x * blockDim.x + threadIdx.x;
    if (e < E) atomicAdd(&cnt[dst[e]], 1);
}

__global__ __launch_bounds__(256)
void block_sum_kernel(const int* __restrict__ cnt, int* __restrict__ bsum, int n)
{
    __shared__ int sh[256];
    int t = threadIdx.x;
    int i = blockIdx.x * 256 + t;
    sh[t] = (i < n) ? cnt[i] : 0;
    __syncthreads();
    #pragma unroll
    for (int off = 128; off > 0; off >>= 1) {
        if (t < off) sh[t] += sh[t + off];
        __syncthreads();
    }
    if (t == 0) bsum[blockIdx.x] = sh[0];
}

__global__ __launch_bounds__(256)
void scan_bsum_kernel(int* __restrict__ bsum, int* __restrict__ row_start, int nb, int n)
{
    __shared__ int sh[256];
    int t = threadIdx.x;
    int v = (t < nb) ? bsum[t] : 0;
    sh[t] = v;
    __syncthreads();
    #pragma unroll
    for (int off = 1; off < 256; off <<= 1) {
        int xv = (t >= off) ? sh[t - off] : 0;
        __syncthreads();
        sh[t] += xv;
        __syncthreads();
    }
    if (t < nb) bsum[t] = sh[t] - v;
    if (t == 255) row_start[n] = sh[255];
}

__global__ __launch_bounds__(256)
void scan_final_kernel(const int* __restrict__ cnt, const int* __restrict__ boff,
                       int* __restrict__ row_start, int* __restrict__ cursor, int n)
{
    __shared__ int sh[256];
    int t = threadIdx.x;
    int i = blockIdx.x * 256 + t;
    int v = (i < n) ? cnt[i] : 0;
    sh[t] = v;
    __syncthreads();
    #pragma unroll
    for (int off = 1; off < 256; off <<= 1) {
        int xv = (t >= off) ? sh[t - off] : 0;
        __syncthreads();
        sh[t] += xv;
        __syncthreads();
    }
    if (i < n) {
        int ex = boff[blockIdx.x] + sh[t] - v;
        row_start[i] = ex;
        cursor[i]    = ex;
    }
}

__global__ void scatter_edges_kernel(const int* __restrict__ dst, const int* __restrict__ src,
                                     const float* __restrict__ ea, int* cursor,
                                     int2* __restrict__ recs, int E)
{
    int e = blockIdx.x * blockDim.x + threadIdx.x;
    if (e < E) {
        int p = atomicAdd(&cursor[dst[e]], 1);
        recs[p] = make_int2(src[e], __float_as_int(ea[e]));
    }
}

// ---------------------------------------------------------------------------
// Fused GATv2: one wave per dst node; 4x16-lane groups process 4 edges
// concurrently; lane owns 8 dims (f16 xlr rows: [xl|xr] 256 f16 per node).
// ---------------------------------------------------------------------------
__global__ __launch_bounds__(256)
void gat_aggregate_kernel(const _Float16* __restrict__ xlr, const int2* __restrict__ recs,
                          const float* __restrict__ We, const float* __restrict__ att,
                          const float* __restrict__ bg, const int* __restrict__ row_start,
                          _Float16* __restrict__ z, int n)
{
    const int wave = threadIdx.x >> 6;
    const int lane = threadIdx.x & 63;
    const int node = blockIdx.x * 4 + wave;
    if (node >= n) return;

    const int g  = lane >> 4;
    const int sl = lane & 15;
    const int d0 = sl * 8;

    float at8[8], we8[8], xr8[8];
    {
        float4 a0 = *(const float4*)(att + d0);
        float4 a1 = *(const float4*)(att + d0 + 4);
        float4 w0 = *(const float4*)(We + d0);
        float4 w1 = *(const float4*)(We + d0 + 4);
        at8[0]=a0.x; at8[1]=a0.y; at8[2]=a0.z; at8[3]=a0.w;
        at8[4]=a1.x; at8[5]=a1.y; at8[6]=a1.z; at8[7]=a1.w;
        we8[0]=w0.x; we8[1]=w0.y; we8[2]=w0.z; we8[3]=w0.w;
        we8[4]=w1.x; we8[5]=w1.y; we8[6]=w1.z; we8[7]=w1.w;
        half8 xh = *(const half8*)(xlr + (size_t)node * 256 + 128 + d0);
        #pragma unroll
        for (int j = 0; j < 8; ++j) xr8[j] = (float)xh[j];
    }

    const int beg = row_start[node];
    const int end = row_start[node + 1];

    float m_run = -INFINITY;
    float l_run = 0.f;
    float acc[8];
    #pragma unroll
    for (int j = 0; j < 8; ++j) acc[j] = 0.f;

    for (int idx = beg + g; idx < end; idx += 4) {
        int2 rec  = recs[idx];
        float eav = __int_as_float(rec.y);
        half8 xh  = *(const half8*)(xlr + (size_t)rec.x * 256 + d0);

        float part = 0.f;
        float xv[8];
        #pragma unroll
        for (int j = 0; j < 8; ++j) {
            float xj = (float)xh[j];
            xv[j] = xj;
            float m = xj + xr8[j] + eav * we8[j];
            m = (m > 0.f) ? m : NEG_SLOPE * m;
            part += m * at8[j];
        }
        part += __shfl_xor(part, 1);
        part += __shfl_xor(part, 2);
        part += __shfl_xor(part, 4);
        part += __shfl_xor(part, 8);

        float mn = fmaxf(m_run, part);
        float sc = expf(m_run - mn);   // 0 on first iteration
        float p  = expf(part - mn);
        l_run = l_run * sc + p;
        #pragma unroll
        for (int j = 0; j < 8; ++j) acc[j] = acc[j] * sc + p * xv[j];
        m_run = mn;
    }

    // merge the 4 group states; guard scale=1 when m==mn (handles empty/empty)
    #pragma unroll
    for (int off = 16; off <= 32; off <<= 1) {
        float m_o = __shfl_xor(m_run, off);
        float l_o = __shfl_xor(l_run, off);
        float mn  = fmaxf(m_run, m_o);
        float sa  = (m_run == mn) ? 1.f : expf(m_run - mn);
        float sb  = (m_o   == mn) ? 1.f : expf(m_o - mn);
        l_run = l_run * sa + l_o * sb;
        #pragma unroll
        for (int j = 0; j < 8; ++j) {
            float a_o = __shfl_xor(acc[j], off);
            acc[j] = acc[j] * sa + a_o * sb;
        }
        m_run = mn;
    }

    if (g == 0) {
        float inv = (l_run > 0.f) ? 1.f / l_run : 0.f;
        const float* bgp = bg + d0;
        half8 o;
        #pragma unroll
        for (int j = 0; j < 8; ++j) {
            float v = fmaxf(acc[j] * inv + bgp[j], 0.f);
            o[j] = (_Float16)v;
        }
        *(half8*)(z + (size_t)node * 128 + d0) = o;
    }
}

// ---------------------------------------------------------------------------
// Decoder layer 2 + softmax, f32 out
// ---------------------------------------------------------------------------
__global__ __launch_bounds__(256)
void dec2_softmax_kernel(const float* __restrict__ d, const float* __restrict__ Wd2,
                         const float* __restrict__ bd2, float* __restrict__ out,
                         int n)
{
    __shared__ float wsm[64 * 10];
    __shared__ float bsm[10];
    const int t = threadIdx.x;
    for (int i = t; i < 640; i += 256) wsm[i] = Wd2[i];
    if (t < 10) bsm[t] = bd2[t];
    __syncthreads();

    int node = blockIdx.x * 256 + t;
    if (node >= n) return;

    const float* dr = d + (size_t)node * 64;
    float logits[10];
    #pragma unroll
    for (int c = 0; c < 10; ++c) logits[c] = bsm[c];
    for (int k = 0; k < 64; k += 4) {
        float4 dv = *(const float4*)(dr + k);
        #pragma unroll
        for (int c = 0; c < 10; ++c) {
            logits[c] += dv.x * wsm[(k + 0) * 10 + c];
            logits[c] += dv.y * wsm[(k + 1) * 10 + c];
            logits[c] += dv.z * wsm[(k + 2) * 10 + c];
            logits[c] += dv.w * wsm[(k + 3) * 10 + c];
        }
    }
    float mx = logits[0];
    #pragma unroll
    for (int c = 1; c < 10; ++c) mx = fmaxf(mx, logits[c]);
    float ssum = 0.f;
    #pragma unroll
    for (int c = 0; c < 10; ++c) { logits[c] = expf(logits[c] - mx); ssum += logits[c]; }
    float inv = 1.f / ssum;
    #pragma unroll
    for (int c = 0; c < 10; ++c)
        out[(size_t)node * 10 + c] = logits[c] * inv;
}

// ---------------------------------------------------------------------------
// Launch
// ---------------------------------------------------------------------------
extern "C" void kernel_launch(void* const* d_in, const int* in_sizes, int n_in,
                              void* d_out, int out_size, void* d_ws, size_t ws_size,
                              hipStream_t stream)
{
    const float* x    = (const float*)d_in[0];
    const float* pos  = (const float*)d_in[1];
    const int*   ei   = (const int*)d_in[2];
    const float* ea   = (const float*)d_in[3];
    const float* W1   = (const float*)d_in[4];
    const float* b1   = (const float*)d_in[5];
    const float* W2   = (const float*)d_in[6];
    const float* b2   = (const float*)d_in[7];
    const float* W3   = (const float*)d_in[8];
    const float* b3   = (const float*)d_in[9];
    const float* Wl   = (const float*)d_in[10];
    const float* bl   = (const float*)d_in[11];
    const float* Wr   = (const float*)d_in[12];
    const float* br   = (const float*)d_in[13];
    const float* We   = (const float*)d_in[14];
    const float* att  = (const float*)d_in[15];
    const float* bg   = (const float*)d_in[16];
    const float* Wd1  = (const float*)d_in[17];
    const float* bd1  = (const float*)d_in[18];
    const float* Wd2  = (const float*)d_in[19];
    const float* bd2  = (const float*)d_in[20];
    float* out = (float*)d_out;

    const int N = in_sizes[0] / 500;   // 50000
    const int E = in_sizes[2] / 2;     // 800000

    // ---- workspace layout (bytes) ----
    char* base = (char*)d_ws;
    const size_t szR = (size_t)N * 512 * 2;   // 51.2 MB region size
    // region 0: A0h -> (dead after GEMM1) h2h, hh, zh; dd reuses base later
    _Float16* A0h = (_Float16*)(base);                            // N*512 f16
    _Float16* h2h = (_Float16*)(base);                            // N*256 f16
    _Float16* hh  = (_Float16*)(base + (size_t)N * 256 * 2);      // N*128 f16
    _Float16* zh  = (_Float16*)(base + (size_t)N * 384 * 2);      // N*128 f16
    float*    dd  = (float*)(base);                               // N*64 f32 (h2h dead)
    // region 1: h1h -> xlr
    char* r1 = base + szR;
    _Float16* h1h = (_Float16*)(r1);                              // N*512 f16
    _Float16* xlr = (_Float16*)(r1);                              // N*256 f16 (h1h dead)
    // region 2: weights + CSR
    char* r2 = base + 2 * szR;
    _Float16* W1t   = (_Float16*)(r2);                // 512*512
    _Float16* W2t   = W1t  + 512 * 512;               // 256*512
    _Float16* W3t   = W2t  + 256 * 512;               // 128*256
    _Float16* Wlrt  = W3t  + 128 * 256;               // 256*128
    _Float16* Wd1t  = Wlrt + 256 * 128;               // 64*128
    float*    blr   = (float*)(Wd1t + 64 * 128);      // 256 f32
    int* cnt       = (int*)(r2 + 2 * 1024 * 1024);
    int* row_start = cnt + N;
    int* bsum      = row_start + N + 1;
    int2* recs     = (int2*)(r2 + 3 * 1024 * 1024);   // E * 8 bytes

    const int* srcArr = ei;
    const int* dstArr = ei + E;
    const int gx = (N + 127) / 128;
    const int nb = (N + 255) / 256;

    // ---- input/weight conversions ----
    concat_f16_kernel<<<2048, 256, 0, stream>>>(x, pos, A0h, N);
    wconv_kernel<<<1024, 256, 0, stream>>>(W1,  W1t,  502, 512, 512);
    wconv_kernel<<<512,  256, 0, stream>>>(W2,  W2t,  512, 256, 512);
    wconv_kernel<<<128,  256, 0, stream>>>(W3,  W3t,  256, 128, 256);
    wconv_lr_kernel<<<128, 256, 0, stream>>>(Wl, Wr, bl, br, Wlrt, blr);
    wconv_kernel<<<32,   256, 0, stream>>>(Wd1, Wd1t, 128, 64,  128);

    // ---- CSR build ----
    init_cnt_kernel<<<256, 256, 0, stream>>>(cnt, N);
    count_edges_kernel<<<(E + 255) / 256, 256, 0, stream>>>(dstArr, cnt, E);
    block_sum_kernel<<<nb, 256, 0, stream>>>(cnt, bsum, N);
    scan_bsum_kernel<<<1, 256, 0, stream>>>(bsum, row_start, nb, N);
    scan_final_kernel<<<nb, 256, 0, stream>>>(cnt, bsum, row_start, cnt, N);
    scatter_edges_kernel<<<(E + 255) / 256, 256, 0, stream>>>(dstArr, srcArr, ea, cnt, recs, E);

    // ---- encoder ----
    gemm_f16_kernel<0,1><<<gx * 4, 256, 0, stream>>>(A0h, W1t, b1, nullptr, h1h, N, 512, 512, 4, 1);
    gemm_f16_kernel<0,1><<<gx * 2, 256, 0, stream>>>(h1h, W2t, b2, nullptr, h2h, N, 256, 512, 2, 1);
    gemm_f16_kernel<0,1><<<gx * 1, 256, 0, stream>>>(h2h, W3t, b3, nullptr, hh,  N, 128, 256, 1, 0);
    // ---- combined xl|xr transform -> xlr f16 ----
    gemm_f16_kernel<0,1><<<gx * 2, 256, 0, stream>>>(hh, Wlrt, blr, nullptr, xlr, N, 256, 128, 2, 0);

    // ---- fused GATv2 softmax + aggregation ----
    gat_aggregate_kernel<<<(N + 3) / 4, 256, 0, stream>>>(xlr, recs, We, att, bg,
                                                          row_start, zh, N);

    // ---- decoder ----
    gemm_f16_kernel<1,0><<<gx * 1, 256, 0, stream>>>(zh, Wd1t, bd1, dd, nullptr, N, 64, 128, 1, 1);
    dec2_softmax_kernel<<<(N + 255) / 256, 256, 0, stream>>>(dd, Wd2, bd2, out, N);
}